// Round 23
// baseline (136.702 us; speedup 1.0000x reference)
//
#include <hip/hip_runtime.h>
#include <hip/hip_bf16.h>

// ---------------------------------------------------------------------------
// CosineAttention forward.  b=16, c=512, h=w=32 -> seq=1024, heads=8, hd=64.
//
// Pipeline (matmuls bf16 MFMA, fp32 accumulate):
//  1) prep_kernel  : fused wnorm (bf16 weights, wn_attn rows rho-permuted)
//                    + x transpose (x_t bf16 [b][s][c])
//  2) gemm_qkv     : QKV gemm (BK=64) + FUSED pixel_norm + repack epilogue
//  3) attn_mfma    : flash attention, R13 schedule + split-softmax/PV
//                    interleave (softmax(s0)->PV01 || softmax(s1)->PV23)
//  4) gemm_proj    : out = mp_add(x, wn_proj @ y); LDS-staged coalesced epi
// ---------------------------------------------------------------------------

typedef __attribute__((ext_vector_type(8))) short short8;
typedef __attribute__((ext_vector_type(8))) unsigned short ushort8;
typedef __attribute__((ext_vector_type(4))) float f32x4;
typedef __attribute__((ext_vector_type(16))) float f32x16;
typedef __attribute__((ext_vector_type(4))) unsigned int uint4_t;

__device__ inline unsigned short f2bf(float v) {
  __hip_bfloat16 h = __float2bfloat16(v);
  return *reinterpret_cast<unsigned short*>(&h);
}
__device__ inline float bf2f(unsigned short u) {
  return __uint_as_float((unsigned)u << 16);
}
__device__ inline unsigned cvt_pk(float lo, float hi) {
  unsigned r;
  asm("v_cvt_pk_bf16_f32 %0, %1, %2" : "=v"(r) : "v"(lo), "v"(hi));
  return r;
}
// raw hardware exp2: inputs bounded |x| <= 92.4 (pixel_norm bound) -> always
// normal results, no OCML denormal guard needed.
__device__ inline float fexp2(float x) {
#if __has_builtin(__builtin_amdgcn_exp2f)
  return __builtin_amdgcn_exp2f(x);
#else
  float r;
  asm("v_exp_f32 %0, %1\n\ts_nop 0" : "=v"(r) : "v"(x));
  return r;
#endif
}
__device__ inline float frsq(float x) {
#if __has_builtin(__builtin_amdgcn_rsqf)
  return __builtin_amdgcn_rsqf(x);
#else
  return rsqrtf(x);
#endif
}
__device__ inline void gload16(const void* g, void* l) {
  __builtin_amdgcn_global_load_lds(
      (const __attribute__((address_space(1))) unsigned int*)g,
      (__attribute__((address_space(3))) unsigned int*)l, 16, 0, 0);
}

// ---------------- fused weight-norm + x-transpose --------------------------
// bid < 2048: weight row normalization (wn_attn rows rho-permuted).
// bid >= 2048: x fp32 [b][c][s] -> x_t bf16 [b][s][c] 64x64 tile transpose.
__global__ __launch_bounds__(256) void prep_kernel(
    const float* __restrict__ wa, const float* __restrict__ wp,
    __hip_bfloat16* __restrict__ wna, __hip_bfloat16* __restrict__ wnp,
    const float* __restrict__ x, __hip_bfloat16* __restrict__ xt) {
  __shared__ __align__(16) unsigned short trans[64][68];
  __shared__ float wsum[4];
  int bid = blockIdx.x;
  int t = threadIdx.x;
  if (bid < 2048) {
    int o = bid;
    const float* src;
    __hip_bfloat16* dst;
    if (o < 1536) {
      int g = o >> 9, rem = o & 511, n = rem >> 6, d = rem & 63;
      int row = g * 512 + (d >> 4) * 128 + n * 16 + (d & 15);
      src = wa + (size_t)o * 512;
      dst = wna + (size_t)row * 512;
    } else {
      src = wp + (size_t)(o - 1536) * 512;
      dst = wnp + (size_t)(o - 1536) * 512;
    }
    float a = src[t], b = src[t + 256];
    float ss = a * a + b * b;
#pragma unroll
    for (int off = 32; off > 0; off >>= 1) ss += __shfl_down(ss, off, 64);
    if ((t & 63) == 0) wsum[t >> 6] = ss;
    __syncthreads();
    float tot = wsum[0] + wsum[1] + wsum[2] + wsum[3];
    float r = 1.0f / (sqrtf(tot) + 2.2627416997969522e-3f);  // n + EPS*sqrt(512)
    dst[t] = __float2bfloat16(a * r);
    dst[t + 256] = __float2bfloat16(b * r);
    return;
  }
  int bid2 = bid - 2048;
  int s0 = (bid2 & 15) * 64;
  int c0 = ((bid2 >> 4) & 7) * 64;
  int b = bid2 >> 7;
  int sl = t & 63, cg = t >> 6;
  const float* src = x + (size_t)b * 524288 + (size_t)(c0 + cg * 16) * 1024 + s0 + sl;
#pragma unroll
  for (int i = 0; i < 16; i += 2) {
    float v0 = src[(size_t)i * 1024];
    float v1 = src[(size_t)(i + 1) * 1024];
    *(unsigned*)&trans[sl][cg * 16 + i] = (unsigned)f2bf(v0) | ((unsigned)f2bf(v1) << 16);
  }
  __syncthreads();
  int sw = t >> 2, cw = (t & 3) * 16;
  __hip_bfloat16* dst = xt + (size_t)b * 524288 + (size_t)(s0 + sw) * 512 + c0 + cw;
  uint2 r0 = *(uint2*)&trans[sw][cw + 0];
  uint2 r1 = *(uint2*)&trans[sw][cw + 4];
  uint2 r2 = *(uint2*)&trans[sw][cw + 8];
  uint2 r3 = *(uint2*)&trans[sw][cw + 12];
  uint4 o0 = {r0.x, r0.y, r1.x, r1.y};
  uint4 o1 = {r2.x, r2.y, r3.x, r3.y};
  *(uint4*)dst = o0;
  *(uint4*)((char*)dst + 16) = o1;
}

// ---------------- fused QKV GEMM + pixel_norm + repack ---------------------
__global__ __launch_bounds__(256) void gemm_qkv(
    const __hip_bfloat16* __restrict__ A, const __hip_bfloat16* __restrict__ B,
    __hip_bfloat16* __restrict__ q_sd, __hip_bfloat16* __restrict__ k_sd,
    __hip_bfloat16* __restrict__ v_ds) {
  __shared__ __align__(16) char smem[65536];
  char* AlB = smem;            // 2 x 16384
  char* BlB = smem + 32768;    // 2 x 16384
  int t = threadIdx.x;
  int w = t >> 6, l = t & 63;
  int l15 = l & 15, lg = l >> 4;
  int wm = w >> 1, wn = w & 1;
  int bid = blockIdx.x;
  int xcd = bid & 7;
  int idx = bid >> 3;              // 0..191
  int b = xcd * 2 + (idx >= 96 ? 1 : 0);
  int r = idx >= 96 ? idx - 96 : idx;
  int mt = r >> 3;                 // 0..11
  int n0 = (r & 7) * 128;
  int m0 = mt * 128;
  int g = mt >> 2, dq = mt & 3;

  const char* Ab = (const char*)A + (size_t)m0 * 1024;
  const char* Bb = (const char*)B + (size_t)b * 1048576 + (size_t)n0 * 1024;
  int rl = t >> 3;
  int soff = ((t & 7) * 16) ^ ((rl & 7) << 4);
  const char* asrc = Ab + (size_t)rl * 1024 + soff;
  const char* bsrc = Bb + (size_t)rl * 1024 + soff;

#define STAGE(bi, k0b)                                                       \
  do {                                                                       \
    _Pragma("unroll") for (int i = 0; i < 4; ++i) {                          \
      gload16(asrc + (size_t)i * 32768 + (k0b), AlB + (bi)*16384 + i * 4096 + w * 1024); \
      gload16(bsrc + (size_t)i * 32768 + (k0b), BlB + (bi)*16384 + i * 4096 + w * 1024); \
    }                                                                        \
  } while (0)

  f32x4 acc[4][4];
#pragma unroll
  for (int mi = 0; mi < 4; ++mi)
#pragma unroll
    for (int ni = 0; ni < 4; ++ni) acc[mi][ni] = (f32x4){0.f, 0.f, 0.f, 0.f};

  STAGE(0, 0);
  __syncthreads();

  for (int ks = 0; ks < 8; ++ks) {
    int buf = ks & 1;
    if (ks < 7) STAGE(buf ^ 1, (ks + 1) * 128);
    short8 af[4][2], bf[4][2];
#pragma unroll
    for (int mi = 0; mi < 4; ++mi) {
      int row = wm * 64 + mi * 16 + l15;
      int sw = (row & 7) << 4;
#pragma unroll
      for (int h = 0; h < 2; ++h)
        af[mi][h] = *(const short8*)(AlB + buf * 16384 + row * 128 + ((h * 64 + lg * 16) ^ sw));
    }
#pragma unroll
    for (int ni = 0; ni < 4; ++ni) {
      int row = wn * 64 + ni * 16 + l15;
      int sw = (row & 7) << 4;
#pragma unroll
      for (int h = 0; h < 2; ++h)
        bf[ni][h] = *(const short8*)(BlB + buf * 16384 + row * 128 + ((h * 64 + lg * 16) ^ sw));
    }
    __builtin_amdgcn_s_setprio(1);
#pragma unroll
    for (int mi = 0; mi < 4; ++mi)
#pragma unroll
      for (int ni = 0; ni < 4; ++ni) {
        acc[mi][ni] = __builtin_amdgcn_mfma_f32_16x16x32_bf16(af[mi][0], bf[ni][0], acc[mi][ni], 0, 0, 0);
        acc[mi][ni] = __builtin_amdgcn_mfma_f32_16x16x32_bf16(af[mi][1], bf[ni][1], acc[mi][ni], 0, 0, 0);
      }
    __builtin_amdgcn_s_setprio(0);
    if (ks < 7) __syncthreads();
  }
#undef STAGE

  __syncthreads();  // all frag reads done before LDS reuse

  if (g < 2) {
    unsigned short(*LT)[136] = (unsigned short(*)[136])smem;
#pragma unroll
    for (int mi = 0; mi < 4; ++mi)
#pragma unroll
      for (int ni = 0; ni < 4; ++ni) {
        int sl = wn * 64 + ni * 16 + l15;
        int lr0 = wm * 64 + mi * 16 + lg * 4;
        *(unsigned*)&LT[sl][lr0] = cvt_pk(acc[mi][ni][0], acc[mi][ni][1]);
        *(unsigned*)&LT[sl][lr0 + 2] = cvt_pk(acc[mi][ni][2], acc[mi][ni][3]);
      }
    __syncthreads();
    int s = t >> 1, dd8 = (t & 1) * 8;
    ushort8 v[8];
#pragma unroll
    for (int n = 0; n < 8; ++n) v[n] = *(ushort8*)&LT[s][n * 16 + dd8];
    float f[8];
#pragma unroll
    for (int j = 0; j < 8; ++j) {
      float ss = 0.f;
#pragma unroll
      for (int n = 0; n < 8; ++n) { float xv = bf2f(v[n][j]); ss += xv * xv; }
      f[j] = frsq(ss * 0.125f + 1e-4f);
    }
    if (g == 0) {
#pragma unroll
      for (int j = 0; j < 8; ++j) f[j] *= 0.18033688011112042f;  // 0.125*log2e
    }
    unsigned short* dstb = (unsigned short*)(g ? k_sd : q_sd) +
        ((size_t)(b * 8) * 1024 + n0 + s) * 64 + dq * 16 + dd8;
#pragma unroll
    for (int n = 0; n < 8; ++n) {
      uint4 o;
      o.x = cvt_pk(bf2f(v[n][0]) * f[0], bf2f(v[n][1]) * f[1]);
      o.y = cvt_pk(bf2f(v[n][2]) * f[2], bf2f(v[n][3]) * f[3]);
      o.z = cvt_pk(bf2f(v[n][4]) * f[4], bf2f(v[n][5]) * f[5]);
      o.w = cvt_pk(bf2f(v[n][6]) * f[6], bf2f(v[n][7]) * f[7]);
      *(uint4*)(dstb + (size_t)n * 65536) = o;
    }
  } else {
    unsigned short(*L)[136] = (unsigned short(*)[136])smem;
#pragma unroll
    for (int mi = 0; mi < 4; ++mi)
#pragma unroll
      for (int ni = 0; ni < 4; ++ni) {
        int sl = wn * 64 + ni * 16 + l15;
        int lr0 = wm * 64 + mi * 16 + lg * 4;
#pragma unroll
        for (int rr = 0; rr < 4; ++rr) L[lr0 + rr][sl] = f2bf(acc[mi][ni][rr]);
      }
    __syncthreads();
    int dd = t >> 4, s0 = (t & 15) * 8;
    ushort8 v[8];
#pragma unroll
    for (int n = 0; n < 8; ++n) v[n] = *(ushort8*)&L[n * 16 + dd][s0];
    float f[8];
#pragma unroll
    for (int j = 0; j < 8; ++j) {
      float ss = 0.f;
#pragma unroll
      for (int n = 0; n < 8; ++n) { float xv = bf2f(v[n][j]); ss += xv * xv; }
      f[j] = frsq(ss * 0.125f + 1e-4f);
    }
    unsigned short* dstb = (unsigned short*)v_ds +
        ((size_t)(b * 8) * 64 + dq * 16 + dd) * 1024 + n0 + s0;
#pragma unroll
    for (int n = 0; n < 8; ++n) {
      uint4 o;
      o.x = cvt_pk(bf2f(v[n][0]) * f[0], bf2f(v[n][1]) * f[1]);
      o.y = cvt_pk(bf2f(v[n][2]) * f[2], bf2f(v[n][3]) * f[3]);
      o.z = cvt_pk(bf2f(v[n][4]) * f[4], bf2f(v[n][5]) * f[5]);
      o.w = cvt_pk(bf2f(v[n][6]) * f[6], bf2f(v[n][7]) * f[7]);
      *(uint4*)(dstb + (size_t)n * 65536) = o;
    }
  }
}

// ---------------- proj GEMM:  out = mp_add(x, wn_proj @ y_t) ---------------
// K-loop identical to R18. Epilogue: stage the 128x128 fp32 C-tile through
// LDS in two 64-row halves ([64][132] padded), then mp_add with fully
// coalesced float4 resid reads / out writes.
__global__ __launch_bounds__(256) void gemm_proj(
    const __hip_bfloat16* __restrict__ A, const __hip_bfloat16* __restrict__ B,
    float* __restrict__ Out, const float* __restrict__ resid, int M) {
  __shared__ __align__(16) char smem[65536];
  char* Al = smem;            // 2 x 16384
  char* Bl = smem + 32768;    // 2 x 16384
  int t = threadIdx.x;
  int w = t >> 6, l = t & 63;
  int l15 = l & 15, lg = l >> 4;
  int wm = w >> 1, wn = w & 1;
  int bid = blockIdx.x;
  int mt = M >> 7;
  int half_ = mt * 8;
  int xcd = bid & 7;
  int idx = bid >> 3;
  int b = xcd * 2 + (idx >= half_ ? 1 : 0);
  int r = idx >= half_ ? idx - half_ : idx;
  int m0 = (r >> 3) * 128, n0 = (r & 7) * 128;

  const char* Ab = (const char*)A + (size_t)m0 * 1024;
  const char* Bb = (const char*)B + (size_t)b * 1048576 + (size_t)n0 * 1024;
  int rl = t >> 3;
  int soff = ((t & 7) * 16) ^ ((rl & 7) << 4);
  const char* asrc = Ab + (size_t)rl * 1024 + soff;
  const char* bsrc = Bb + (size_t)rl * 1024 + soff;

#define STAGE(bi, k0b)                                                    \
  do {                                                                    \
    _Pragma("unroll") for (int i = 0; i < 4; ++i) {                       \
      gload16(asrc + (size_t)i * 32768 + (k0b), Al + (bi)*16384 + i * 4096 + w * 1024); \
      gload16(bsrc + (size_t)i * 32768 + (k0b), Bl + (bi)*16384 + i * 4096 + w * 1024); \
    }                                                                     \
  } while (0)

  f32x4 acc[4][4];
#pragma unroll
  for (int mi = 0; mi < 4; ++mi)
#pragma unroll
    for (int ni = 0; ni < 4; ++ni) acc[mi][ni] = (f32x4){0.f, 0.f, 0.f, 0.f};

  STAGE(0, 0);
  __syncthreads();

  for (int ks = 0; ks < 8; ++ks) {
    int buf = ks & 1;
    if (ks < 7) STAGE(buf ^ 1, (ks + 1) * 128);
    short8 af[4][2], bf[4][2];
#pragma unroll
    for (int mi = 0; mi < 4; ++mi) {
      int row = wm * 64 + mi * 16 + l15;
      int sw = (row & 7) << 4;
#pragma unroll
      for (int h = 0; h < 2; ++h)
        af[mi][h] = *(const short8*)(Al + buf * 16384 + row * 128 + ((h * 64 + lg * 16) ^ sw));
    }
#pragma unroll
    for (int ni = 0; ni < 4; ++ni) {
      int row = wn * 64 + ni * 16 + l15;
      int sw = (row & 7) << 4;
#pragma unroll
      for (int h = 0; h < 2; ++h)
        bf[ni][h] = *(const short8*)(Bl + buf * 16384 + row * 128 + ((h * 64 + lg * 16) ^ sw));
    }
    __builtin_amdgcn_s_setprio(1);
#pragma unroll
    for (int mi = 0; mi < 4; ++mi)
#pragma unroll
      for (int ni = 0; ni < 4; ++ni) {
        acc[mi][ni] = __builtin_amdgcn_mfma_f32_16x16x32_bf16(af[mi][0], bf[ni][0], acc[mi][ni], 0, 0, 0);
        acc[mi][ni] = __builtin_amdgcn_mfma_f32_16x16x32_bf16(af[mi][1], bf[ni][1], acc[mi][ni], 0, 0, 0);
      }
    __builtin_amdgcn_s_setprio(0);
    if (ks < 7) __syncthreads();
  }
#undef STAGE

  __syncthreads();  // final-tile frag reads done before LDS reuse
  float* Lc = (float*)smem;  // [64][132] fp32 = 33.8KB
  float* outb = Out + (size_t)b * M * 1024;
  const float* rb = resid + (size_t)b * M * 1024;
#pragma unroll
  for (int hh = 0; hh < 2; ++hh) {
    if (wm == hh) {
#pragma unroll
      for (int mi = 0; mi < 4; ++mi)
#pragma unroll
        for (int ni = 0; ni < 4; ++ni) {
          int rloc = mi * 16 + lg * 4;
          int col = wn * 64 + ni * 16 + l15;
#pragma unroll
          for (int rr = 0; rr < 4; ++rr)
            Lc[(rloc + rr) * 132 + col] = acc[mi][ni][rr];
        }
    }
    __syncthreads();
    int rw = t >> 5;              // 0..7
    int c4 = (t & 31) * 4;        // 0..124
#pragma unroll
    for (int rs = 0; rs < 8; ++rs) {
      int rloc = rw + rs * 8;
      size_t gidx = (size_t)(m0 + hh * 64 + rloc) * 1024 + n0 + c4;
      float4 cv = *(float4*)&Lc[rloc * 132 + c4];
      float4 rv = *(const float4*)(rb + gidx);
      float4 ov;
      ov.x = 0.9191450300180578f * rv.x + 0.39391929857916763f * cv.x;
      ov.y = 0.9191450300180578f * rv.y + 0.39391929857916763f * cv.y;
      ov.z = 0.9191450300180578f * rv.z + 0.39391929857916763f * cv.z;
      ov.w = 0.9191450300180578f * rv.w + 0.39391929857916763f * cv.w;
      *(float4*)(outb + gidx) = ov;
    }
    if (hh == 0) __syncthreads();
  }
}

// ---------------- flash attention, 32x32x16 MFMA, in-register P ------------
// R13 schedule + split-softmax/PV interleave: a_v hoisted above softmax;
// softmax(s0)->pb01->PV(j=0,1) then softmax(s1)->pb23->PV(j=2,3), giving the
// scheduler explicit within-wave VALU||MFMA overlap (PV01 only needs W0).
__global__ __launch_bounds__(512, 4) void attn_mfma(
    const __hip_bfloat16* __restrict__ q_sd, const __hip_bfloat16* __restrict__ k_sd,
    const __hip_bfloat16* __restrict__ v_ds, __hip_bfloat16* __restrict__ y_t) {
  __shared__ __align__(16) char K_lds[2][8192];
  __shared__ __align__(16) char V_lds[2][8192];
  int t = threadIdx.x;
  int w = t >> 6, l = t & 63;
  int l31 = l & 31, h5 = l >> 5;
  int swV = (l31 & 7) << 4;
  int pl = (l31 & 0x13) | ((l31 & 4) << 1) | ((l31 & 8) >> 1);  // swap bits 2,3
  int swK = (pl & 7) << 4;
  int bn = blockIdx.x, qb = blockIdx.y;
  const char* qg = (const char*)(q_sd + (size_t)bn * 65536);   // [s][d]
  const char* kg = (const char*)(k_sd + (size_t)bn * 65536);   // [s][d]
  const char* vg = (const char*)(v_ds + (size_t)bn * 65536);   // [d][s]

  int q = qb * 256 + w * 32 + l31;
  short8 bq[4];
#pragma unroll
  for (int j = 0; j < 4; ++j)
    bq[j] = *(const short8*)(qg + (size_t)q * 128 + j * 32 + h5 * 16);

  f32x16 o_acc[2];
#pragma unroll
  for (int r = 0; r < 16; ++r) { o_acc[0][r] = 0.f; o_acc[1][r] = 0.f; }
  float l_run = 0.f;

  int rowS = t >> 3;
  int offS = (t & 7) * 16;
  int swrS = (rowS & 7) << 4;
  {
    uint4 a = *(const uint4*)(kg + (size_t)t * 16);
    uint4 b2 = *(const uint4*)(vg + (size_t)rowS * 2048 + offS);
    *(uint4*)(K_lds[0] + ((t * 16) ^ swrS)) = a;
    *(uint4*)(V_lds[0] + ((t * 16) ^ swrS)) = b2;
  }
  __syncthreads();

  for (int kb = 0; kb < 16; ++kb) {
    int buf = kb & 1;
    uint4 pk, pv;
    if (kb < 15) {
      pk = *(const uint4*)(kg + (size_t)(kb + 1) * 8192 + (size_t)t * 16);
      pv = *(const uint4*)(vg + (size_t)rowS * 2048 + (size_t)(kb + 1) * 128 + offS);
    }
    short8 a_k[2][4];
#pragma unroll
    for (int kt = 0; kt < 2; ++kt)
#pragma unroll
      for (int j = 0; j < 4; ++j)
        a_k[kt][j] = *(const short8*)(K_lds[buf] +
            (((kt * 32 + pl) * 128 + j * 32 + h5 * 16) ^ swK));
    f32x16 s0, s1;
#pragma unroll
    for (int r = 0; r < 16; ++r) { s0[r] = 0.f; s1[r] = 0.f; }
    __builtin_amdgcn_s_setprio(1);
#pragma unroll
    for (int j = 0; j < 4; ++j) {
      s0 = __builtin_amdgcn_mfma_f32_32x32x16_bf16(a_k[0][j], bq[j], s0, 0, 0, 0);
      s1 = __builtin_amdgcn_mfma_f32_32x32x16_bf16(a_k[1][j], bq[j], s1, 0, 0, 0);
    }
    __builtin_amdgcn_s_setprio(0);
    // ---- V A-frags hoisted above softmax: lgkm latency hides under VALU
    short8 a_v[2][4];
#pragma unroll
    for (int dt = 0; dt < 2; ++dt)
#pragma unroll
      for (int j = 0; j < 4; ++j)
        a_v[dt][j] = *(const short8*)(V_lds[buf] +
            (((dt * 32 + l31) * 128 + j * 32 + h5 * 16) ^ swV));
    // ---- half 1: softmax(s0) -> pb01 -> PV j=0,1
    unsigned W0[8];
    float ts0 = 0.f;
#pragma unroll
    for (int m = 0; m < 8; ++m) {
      float p0 = fexp2(s0[2 * m]), p1 = fexp2(s0[2 * m + 1]);
      ts0 += p0 + p1;
      W0[m] = cvt_pk(p0, p1);
    }
    short8 pb0 = __builtin_bit_cast(short8, (uint4_t){W0[0], W0[1], W0[2], W0[3]});
    short8 pb1 = __builtin_bit_cast(short8, (uint4_t){W0[4], W0[5], W0[6], W0[7]});
    o_acc[0] = __builtin_amdgcn_mfma_f32_32x32x16_bf16(a_v[0][0], pb0, o_acc[0], 0, 0, 0);
    o_acc[1] = __builtin_amdgcn_mfma_f32_32x32x16_bf16(a_v[1][0], pb0, o_acc[1], 0, 0, 0);
    o_acc[0] = __builtin_amdgcn_mfma_f32_32x32x16_bf16(a_v[0][1], pb1, o_acc[0], 0, 0, 0);
    o_acc[1] = __builtin_amdgcn_mfma_f32_32x32x16_bf16(a_v[1][1], pb1, o_acc[1], 0, 0, 0);
    // ---- half 2: softmax(s1) -> pb23 -> PV j=2,3 (overlaps PV01 MFMA)
    unsigned W1[8];
    float ts1 = 0.f;
#pragma unroll
    for (int m = 0; m < 8; ++m) {
      float p2 = fexp2(s1[2 * m]), p3 = fexp2(s1[2 * m + 1]);
      ts1 += p2 + p3;
      W1[m] = cvt_pk(p2, p3);
    }
    short8 pb2 = __builtin_bit_cast(short8, (uint4_t){W1[0], W1[1], W1[2], W1[3]});
    short8 pb3 = __builtin_bit_cast(short8, (uint4_t){W1[4], W1[5], W1[6], W1[7]});
    o_acc[0] = __builtin_amdgcn_mfma_f32_32x32x16_bf16(a_v[0][2], pb2, o_acc[0], 0, 0, 0);
    o_acc[1] = __builtin_amdgcn_mfma_f32_32x32x16_bf16(a_v[1][2], pb2, o_acc[1], 0, 0, 0);
    o_acc[0] = __builtin_amdgcn_mfma_f32_32x32x16_bf16(a_v[0][3], pb3, o_acc[0], 0, 0, 0);
    o_acc[1] = __builtin_amdgcn_mfma_f32_32x32x16_bf16(a_v[1][3], pb3, o_acc[1], 0, 0, 0);
    l_run += ts0 + ts1;
    if (kb < 15) {
      int nb = buf ^ 1;
      *(uint4*)(K_lds[nb] + ((t * 16) ^ swrS)) = pk;
      *(uint4*)(V_lds[nb] + ((t * 16) ^ swrS)) = pv;
    }
    __syncthreads();
  }
  int b_ = bn >> 3, n_ = bn & 7;
  float lsum = l_run + __shfl_xor(l_run, 32, 64);
  float invl = 1.0f / lsum;
  __hip_bfloat16* yrow = y_t + (size_t)b_ * 524288 + (size_t)q * 512 + n_ * 64 + h5 * 4;
#pragma unroll
  for (int dt = 0; dt < 2; ++dt) {
#pragma unroll
    for (int g4 = 0; g4 < 4; ++g4) {
      uint2 pr;
      pr.x = cvt_pk(o_acc[dt][4 * g4 + 0] * invl, o_acc[dt][4 * g4 + 1] * invl);
      pr.y = cvt_pk(o_acc[dt][4 * g4 + 2] * invl, o_acc[dt][4 * g4 + 3] * invl);
      *(uint2*)(yrow + dt * 32 + g4 * 8) = pr;
    }
  }
}

// ---------------------------------------------------------------------------
extern "C" void kernel_launch(void* const* d_in, const int* in_sizes, int n_in,
                              void* d_out, int out_size, void* d_ws, size_t ws_size,
                              hipStream_t stream) {
  const float* x      = (const float*)d_in[0];  // [16][512][1024]
  const float* w_attn = (const float*)d_in[1];  // [1536][512]
  const float* w_proj = (const float*)d_in[2];  // [512][512]
  float* out = (float*)d_out;

  // workspace (bf16 elements, ~69 MB total)
  __hip_bfloat16* wn_attn = (__hip_bfloat16*)d_ws;        // 786432
  __hip_bfloat16* wn_proj = wn_attn + 786432;             // 262144
  __hip_bfloat16* x_t     = wn_proj + 262144;             // 8388608
  __hip_bfloat16* y_t     = x_t;                          // alias (x_t dead after gemm_qkv)
  __hip_bfloat16* q_sd    = x_t + 8388608;                // 8388608
  __hip_bfloat16* k_sd    = q_sd + 8388608;               // 8388608
  __hip_bfloat16* v_ds    = k_sd + 8388608;               // 8388608

  prep_kernel<<<dim3(4096), dim3(256), 0, stream>>>(w_attn, w_proj, wn_attn, wn_proj, x, x_t);
  gemm_qkv<<<dim3(1536), dim3(256), 0, stream>>>(wn_attn, x_t, q_sd, k_sd, v_ds);
  attn_mfma<<<dim3(128, 4), dim3(512), 0, stream>>>(q_sd, k_sd, v_ds, y_t);
  gemm_proj<<<dim3(512), dim3(256), 0, stream>>>(wn_proj, y_t, out, x, 512);
}

// Round 24
// 115.811 us; speedup vs baseline: 1.1804x; 1.1804x over previous
//
#include <hip/hip_runtime.h>
#include <hip/hip_bf16.h>

// ---------------------------------------------------------------------------
// CosineAttention forward.  b=16, c=512, h=w=32 -> seq=1024, heads=8, hd=64.
//
// Pipeline (matmuls bf16 MFMA, fp32 accumulate):
//  1) prep_kernel  : fused wnorm (bf16 weights, wn_attn rows rho-permuted)
//                    + x transpose (x_t bf16 [b][s][c])
//  2) gemm_qkv     : QKV gemm (BK=64) + FUSED pixel_norm + repack epilogue
//  3) attn_mfma    : flash attention, R13 schedule (measured optimum; the
//                    serial QK->softmax->PV phase order + early-issue reg
//                    prefetch is load-bearing for inter-block L2 reuse —
//                    R23's interleave broke it, +18MB FETCH)
//  4) gemm_proj    : out = mp_add(x, wn_proj @ y); LDS-staged coalesced epi
// ---------------------------------------------------------------------------

typedef __attribute__((ext_vector_type(8))) short short8;
typedef __attribute__((ext_vector_type(8))) unsigned short ushort8;
typedef __attribute__((ext_vector_type(4))) float f32x4;
typedef __attribute__((ext_vector_type(16))) float f32x16;
typedef __attribute__((ext_vector_type(4))) unsigned int uint4_t;

__device__ inline unsigned short f2bf(float v) {
  __hip_bfloat16 h = __float2bfloat16(v);
  return *reinterpret_cast<unsigned short*>(&h);
}
__device__ inline float bf2f(unsigned short u) {
  return __uint_as_float((unsigned)u << 16);
}
__device__ inline unsigned cvt_pk(float lo, float hi) {
  unsigned r;
  asm("v_cvt_pk_bf16_f32 %0, %1, %2" : "=v"(r) : "v"(lo), "v"(hi));
  return r;
}
// raw hardware exp2: inputs bounded |x| <= 92.4 (pixel_norm bound) -> always
// normal results, no OCML denormal guard needed.
__device__ inline float fexp2(float x) {
#if __has_builtin(__builtin_amdgcn_exp2f)
  return __builtin_amdgcn_exp2f(x);
#else
  float r;
  asm("v_exp_f32 %0, %1\n\ts_nop 0" : "=v"(r) : "v"(x));
  return r;
#endif
}
__device__ inline float frsq(float x) {
#if __has_builtin(__builtin_amdgcn_rsqf)
  return __builtin_amdgcn_rsqf(x);
#else
  return rsqrtf(x);
#endif
}
__device__ inline void gload16(const void* g, void* l) {
  __builtin_amdgcn_global_load_lds(
      (const __attribute__((address_space(1))) unsigned int*)g,
      (__attribute__((address_space(3))) unsigned int*)l, 16, 0, 0);
}

// ---------------- fused weight-norm + x-transpose --------------------------
// bid < 2048: weight row normalization (wn_attn rows rho-permuted).
// bid >= 2048: x fp32 [b][c][s] -> x_t bf16 [b][s][c] 64x64 tile transpose.
__global__ __launch_bounds__(256) void prep_kernel(
    const float* __restrict__ wa, const float* __restrict__ wp,
    __hip_bfloat16* __restrict__ wna, __hip_bfloat16* __restrict__ wnp,
    const float* __restrict__ x, __hip_bfloat16* __restrict__ xt) {
  __shared__ __align__(16) unsigned short trans[64][68];
  __shared__ float wsum[4];
  int bid = blockIdx.x;
  int t = threadIdx.x;
  if (bid < 2048) {
    int o = bid;
    const float* src;
    __hip_bfloat16* dst;
    if (o < 1536) {
      int g = o >> 9, rem = o & 511, n = rem >> 6, d = rem & 63;
      int row = g * 512 + (d >> 4) * 128 + n * 16 + (d & 15);
      src = wa + (size_t)o * 512;
      dst = wna + (size_t)row * 512;
    } else {
      src = wp + (size_t)(o - 1536) * 512;
      dst = wnp + (size_t)(o - 1536) * 512;
    }
    float a = src[t], b = src[t + 256];
    float ss = a * a + b * b;
#pragma unroll
    for (int off = 32; off > 0; off >>= 1) ss += __shfl_down(ss, off, 64);
    if ((t & 63) == 0) wsum[t >> 6] = ss;
    __syncthreads();
    float tot = wsum[0] + wsum[1] + wsum[2] + wsum[3];
    float r = 1.0f / (sqrtf(tot) + 2.2627416997969522e-3f);  // n + EPS*sqrt(512)
    dst[t] = __float2bfloat16(a * r);
    dst[t + 256] = __float2bfloat16(b * r);
    return;
  }
  int bid2 = bid - 2048;
  int s0 = (bid2 & 15) * 64;
  int c0 = ((bid2 >> 4) & 7) * 64;
  int b = bid2 >> 7;
  int sl = t & 63, cg = t >> 6;
  const float* src = x + (size_t)b * 524288 + (size_t)(c0 + cg * 16) * 1024 + s0 + sl;
#pragma unroll
  for (int i = 0; i < 16; i += 2) {
    float v0 = src[(size_t)i * 1024];
    float v1 = src[(size_t)(i + 1) * 1024];
    *(unsigned*)&trans[sl][cg * 16 + i] = (unsigned)f2bf(v0) | ((unsigned)f2bf(v1) << 16);
  }
  __syncthreads();
  int sw = t >> 2, cw = (t & 3) * 16;
  __hip_bfloat16* dst = xt + (size_t)b * 524288 + (size_t)(s0 + sw) * 512 + c0 + cw;
  uint2 r0 = *(uint2*)&trans[sw][cw + 0];
  uint2 r1 = *(uint2*)&trans[sw][cw + 4];
  uint2 r2 = *(uint2*)&trans[sw][cw + 8];
  uint2 r3 = *(uint2*)&trans[sw][cw + 12];
  uint4 o0 = {r0.x, r0.y, r1.x, r1.y};
  uint4 o1 = {r2.x, r2.y, r3.x, r3.y};
  *(uint4*)dst = o0;
  *(uint4*)((char*)dst + 16) = o1;
}

// ---------------- fused QKV GEMM + pixel_norm + repack ---------------------
__global__ __launch_bounds__(256) void gemm_qkv(
    const __hip_bfloat16* __restrict__ A, const __hip_bfloat16* __restrict__ B,
    __hip_bfloat16* __restrict__ q_sd, __hip_bfloat16* __restrict__ k_sd,
    __hip_bfloat16* __restrict__ v_ds) {
  __shared__ __align__(16) char smem[65536];
  char* AlB = smem;            // 2 x 16384
  char* BlB = smem + 32768;    // 2 x 16384
  int t = threadIdx.x;
  int w = t >> 6, l = t & 63;
  int l15 = l & 15, lg = l >> 4;
  int wm = w >> 1, wn = w & 1;
  int bid = blockIdx.x;
  int xcd = bid & 7;
  int idx = bid >> 3;              // 0..191
  int b = xcd * 2 + (idx >= 96 ? 1 : 0);
  int r = idx >= 96 ? idx - 96 : idx;
  int mt = r >> 3;                 // 0..11
  int n0 = (r & 7) * 128;
  int m0 = mt * 128;
  int g = mt >> 2, dq = mt & 3;

  const char* Ab = (const char*)A + (size_t)m0 * 1024;
  const char* Bb = (const char*)B + (size_t)b * 1048576 + (size_t)n0 * 1024;
  int rl = t >> 3;
  int soff = ((t & 7) * 16) ^ ((rl & 7) << 4);
  const char* asrc = Ab + (size_t)rl * 1024 + soff;
  const char* bsrc = Bb + (size_t)rl * 1024 + soff;

#define STAGE(bi, k0b)                                                       \
  do {                                                                       \
    _Pragma("unroll") for (int i = 0; i < 4; ++i) {                          \
      gload16(asrc + (size_t)i * 32768 + (k0b), AlB + (bi)*16384 + i * 4096 + w * 1024); \
      gload16(bsrc + (size_t)i * 32768 + (k0b), BlB + (bi)*16384 + i * 4096 + w * 1024); \
    }                                                                        \
  } while (0)

  f32x4 acc[4][4];
#pragma unroll
  for (int mi = 0; mi < 4; ++mi)
#pragma unroll
    for (int ni = 0; ni < 4; ++ni) acc[mi][ni] = (f32x4){0.f, 0.f, 0.f, 0.f};

  STAGE(0, 0);
  __syncthreads();

  for (int ks = 0; ks < 8; ++ks) {
    int buf = ks & 1;
    if (ks < 7) STAGE(buf ^ 1, (ks + 1) * 128);
    short8 af[4][2], bf[4][2];
#pragma unroll
    for (int mi = 0; mi < 4; ++mi) {
      int row = wm * 64 + mi * 16 + l15;
      int sw = (row & 7) << 4;
#pragma unroll
      for (int h = 0; h < 2; ++h)
        af[mi][h] = *(const short8*)(AlB + buf * 16384 + row * 128 + ((h * 64 + lg * 16) ^ sw));
    }
#pragma unroll
    for (int ni = 0; ni < 4; ++ni) {
      int row = wn * 64 + ni * 16 + l15;
      int sw = (row & 7) << 4;
#pragma unroll
      for (int h = 0; h < 2; ++h)
        bf[ni][h] = *(const short8*)(BlB + buf * 16384 + row * 128 + ((h * 64 + lg * 16) ^ sw));
    }
    __builtin_amdgcn_s_setprio(1);
#pragma unroll
    for (int mi = 0; mi < 4; ++mi)
#pragma unroll
      for (int ni = 0; ni < 4; ++ni) {
        acc[mi][ni] = __builtin_amdgcn_mfma_f32_16x16x32_bf16(af[mi][0], bf[ni][0], acc[mi][ni], 0, 0, 0);
        acc[mi][ni] = __builtin_amdgcn_mfma_f32_16x16x32_bf16(af[mi][1], bf[ni][1], acc[mi][ni], 0, 0, 0);
      }
    __builtin_amdgcn_s_setprio(0);
    if (ks < 7) __syncthreads();
  }
#undef STAGE

  __syncthreads();  // all frag reads done before LDS reuse

  if (g < 2) {
    unsigned short(*LT)[136] = (unsigned short(*)[136])smem;
#pragma unroll
    for (int mi = 0; mi < 4; ++mi)
#pragma unroll
      for (int ni = 0; ni < 4; ++ni) {
        int sl = wn * 64 + ni * 16 + l15;
        int lr0 = wm * 64 + mi * 16 + lg * 4;
        *(unsigned*)&LT[sl][lr0] = cvt_pk(acc[mi][ni][0], acc[mi][ni][1]);
        *(unsigned*)&LT[sl][lr0 + 2] = cvt_pk(acc[mi][ni][2], acc[mi][ni][3]);
      }
    __syncthreads();
    int s = t >> 1, dd8 = (t & 1) * 8;
    ushort8 v[8];
#pragma unroll
    for (int n = 0; n < 8; ++n) v[n] = *(ushort8*)&LT[s][n * 16 + dd8];
    float f[8];
#pragma unroll
    for (int j = 0; j < 8; ++j) {
      float ss = 0.f;
#pragma unroll
      for (int n = 0; n < 8; ++n) { float xv = bf2f(v[n][j]); ss += xv * xv; }
      f[j] = frsq(ss * 0.125f + 1e-4f);
    }
    if (g == 0) {
#pragma unroll
      for (int j = 0; j < 8; ++j) f[j] *= 0.18033688011112042f;  // 0.125*log2e
    }
    unsigned short* dstb = (unsigned short*)(g ? k_sd : q_sd) +
        ((size_t)(b * 8) * 1024 + n0 + s) * 64 + dq * 16 + dd8;
#pragma unroll
    for (int n = 0; n < 8; ++n) {
      uint4 o;
      o.x = cvt_pk(bf2f(v[n][0]) * f[0], bf2f(v[n][1]) * f[1]);
      o.y = cvt_pk(bf2f(v[n][2]) * f[2], bf2f(v[n][3]) * f[3]);
      o.z = cvt_pk(bf2f(v[n][4]) * f[4], bf2f(v[n][5]) * f[5]);
      o.w = cvt_pk(bf2f(v[n][6]) * f[6], bf2f(v[n][7]) * f[7]);
      *(uint4*)(dstb + (size_t)n * 65536) = o;
    }
  } else {
    unsigned short(*L)[136] = (unsigned short(*)[136])smem;
#pragma unroll
    for (int mi = 0; mi < 4; ++mi)
#pragma unroll
      for (int ni = 0; ni < 4; ++ni) {
        int sl = wn * 64 + ni * 16 + l15;
        int lr0 = wm * 64 + mi * 16 + lg * 4;
#pragma unroll
        for (int rr = 0; rr < 4; ++rr) L[lr0 + rr][sl] = f2bf(acc[mi][ni][rr]);
      }
    __syncthreads();
    int dd = t >> 4, s0 = (t & 15) * 8;
    ushort8 v[8];
#pragma unroll
    for (int n = 0; n < 8; ++n) v[n] = *(ushort8*)&L[n * 16 + dd][s0];
    float f[8];
#pragma unroll
    for (int j = 0; j < 8; ++j) {
      float ss = 0.f;
#pragma unroll
      for (int n = 0; n < 8; ++n) { float xv = bf2f(v[n][j]); ss += xv * xv; }
      f[j] = frsq(ss * 0.125f + 1e-4f);
    }
    unsigned short* dstb = (unsigned short*)v_ds +
        ((size_t)(b * 8) * 64 + dq * 16 + dd) * 1024 + n0 + s0;
#pragma unroll
    for (int n = 0; n < 8; ++n) {
      uint4 o;
      o.x = cvt_pk(bf2f(v[n][0]) * f[0], bf2f(v[n][1]) * f[1]);
      o.y = cvt_pk(bf2f(v[n][2]) * f[2], bf2f(v[n][3]) * f[3]);
      o.z = cvt_pk(bf2f(v[n][4]) * f[4], bf2f(v[n][5]) * f[5]);
      o.w = cvt_pk(bf2f(v[n][6]) * f[6], bf2f(v[n][7]) * f[7]);
      *(uint4*)(dstb + (size_t)n * 65536) = o;
    }
  }
}

// ---------------- proj GEMM:  out = mp_add(x, wn_proj @ y_t) ---------------
// K-loop identical to R18. Epilogue: stage the 128x128 fp32 C-tile through
// LDS in two 64-row halves ([64][132] padded), then mp_add with fully
// coalesced float4 resid reads / out writes.
__global__ __launch_bounds__(256) void gemm_proj(
    const __hip_bfloat16* __restrict__ A, const __hip_bfloat16* __restrict__ B,
    float* __restrict__ Out, const float* __restrict__ resid, int M) {
  __shared__ __align__(16) char smem[65536];
  char* Al = smem;            // 2 x 16384
  char* Bl = smem + 32768;    // 2 x 16384
  int t = threadIdx.x;
  int w = t >> 6, l = t & 63;
  int l15 = l & 15, lg = l >> 4;
  int wm = w >> 1, wn = w & 1;
  int bid = blockIdx.x;
  int mt = M >> 7;
  int half_ = mt * 8;
  int xcd = bid & 7;
  int idx = bid >> 3;
  int b = xcd * 2 + (idx >= half_ ? 1 : 0);
  int r = idx >= half_ ? idx - half_ : idx;
  int m0 = (r >> 3) * 128, n0 = (r & 7) * 128;

  const char* Ab = (const char*)A + (size_t)m0 * 1024;
  const char* Bb = (const char*)B + (size_t)b * 1048576 + (size_t)n0 * 1024;
  int rl = t >> 3;
  int soff = ((t & 7) * 16) ^ ((rl & 7) << 4);
  const char* asrc = Ab + (size_t)rl * 1024 + soff;
  const char* bsrc = Bb + (size_t)rl * 1024 + soff;

#define STAGE(bi, k0b)                                                    \
  do {                                                                    \
    _Pragma("unroll") for (int i = 0; i < 4; ++i) {                       \
      gload16(asrc + (size_t)i * 32768 + (k0b), Al + (bi)*16384 + i * 4096 + w * 1024); \
      gload16(bsrc + (size_t)i * 32768 + (k0b), Bl + (bi)*16384 + i * 4096 + w * 1024); \
    }                                                                     \
  } while (0)

  f32x4 acc[4][4];
#pragma unroll
  for (int mi = 0; mi < 4; ++mi)
#pragma unroll
    for (int ni = 0; ni < 4; ++ni) acc[mi][ni] = (f32x4){0.f, 0.f, 0.f, 0.f};

  STAGE(0, 0);
  __syncthreads();

  for (int ks = 0; ks < 8; ++ks) {
    int buf = ks & 1;
    if (ks < 7) STAGE(buf ^ 1, (ks + 1) * 128);
    short8 af[4][2], bf[4][2];
#pragma unroll
    for (int mi = 0; mi < 4; ++mi) {
      int row = wm * 64 + mi * 16 + l15;
      int sw = (row & 7) << 4;
#pragma unroll
      for (int h = 0; h < 2; ++h)
        af[mi][h] = *(const short8*)(Al + buf * 16384 + row * 128 + ((h * 64 + lg * 16) ^ sw));
    }
#pragma unroll
    for (int ni = 0; ni < 4; ++ni) {
      int row = wn * 64 + ni * 16 + l15;
      int sw = (row & 7) << 4;
#pragma unroll
      for (int h = 0; h < 2; ++h)
        bf[ni][h] = *(const short8*)(Bl + buf * 16384 + row * 128 + ((h * 64 + lg * 16) ^ sw));
    }
    __builtin_amdgcn_s_setprio(1);
#pragma unroll
    for (int mi = 0; mi < 4; ++mi)
#pragma unroll
      for (int ni = 0; ni < 4; ++ni) {
        acc[mi][ni] = __builtin_amdgcn_mfma_f32_16x16x32_bf16(af[mi][0], bf[ni][0], acc[mi][ni], 0, 0, 0);
        acc[mi][ni] = __builtin_amdgcn_mfma_f32_16x16x32_bf16(af[mi][1], bf[ni][1], acc[mi][ni], 0, 0, 0);
      }
    __builtin_amdgcn_s_setprio(0);
    if (ks < 7) __syncthreads();
  }
#undef STAGE

  __syncthreads();  // final-tile frag reads done before LDS reuse
  float* Lc = (float*)smem;  // [64][132] fp32 = 33.8KB
  float* outb = Out + (size_t)b * M * 1024;
  const float* rb = resid + (size_t)b * M * 1024;
#pragma unroll
  for (int hh = 0; hh < 2; ++hh) {
    if (wm == hh) {
#pragma unroll
      for (int mi = 0; mi < 4; ++mi)
#pragma unroll
        for (int ni = 0; ni < 4; ++ni) {
          int rloc = mi * 16 + lg * 4;
          int col = wn * 64 + ni * 16 + l15;
#pragma unroll
          for (int rr = 0; rr < 4; ++rr)
            Lc[(rloc + rr) * 132 + col] = acc[mi][ni][rr];
        }
    }
    __syncthreads();
    int rw = t >> 5;              // 0..7
    int c4 = (t & 31) * 4;        // 0..124
#pragma unroll
    for (int rs = 0; rs < 8; ++rs) {
      int rloc = rw + rs * 8;
      size_t gidx = (size_t)(m0 + hh * 64 + rloc) * 1024 + n0 + c4;
      float4 cv = *(float4*)&Lc[rloc * 132 + c4];
      float4 rv = *(const float4*)(rb + gidx);
      float4 ov;
      ov.x = 0.9191450300180578f * rv.x + 0.39391929857916763f * cv.x;
      ov.y = 0.9191450300180578f * rv.y + 0.39391929857916763f * cv.y;
      ov.z = 0.9191450300180578f * rv.z + 0.39391929857916763f * cv.z;
      ov.w = 0.9191450300180578f * rv.w + 0.39391929857916763f * cv.w;
      *(float4*)(outb + gidx) = ov;
    }
    if (hh == 0) __syncthreads();
  }
}

// ---------------- flash attention, 32x32x16 MFMA, in-register P ------------
// R13 schedule (measured optimum) + zero-seed QK chain (R22, neutral).
// Serial per-tile phases: QK(8 MFMA) -> softmax -> PV(8 MFMA), reg-staged
// early-issue prefetch + XOR ds_write staging. pi-permuted QK^T ->
// lane-local PV B-frags. Max-free softmax, raw v_exp_f32.
__global__ __launch_bounds__(512, 4) void attn_mfma(
    const __hip_bfloat16* __restrict__ q_sd, const __hip_bfloat16* __restrict__ k_sd,
    const __hip_bfloat16* __restrict__ v_ds, __hip_bfloat16* __restrict__ y_t) {
  __shared__ __align__(16) char K_lds[2][8192];
  __shared__ __align__(16) char V_lds[2][8192];
  int t = threadIdx.x;
  int w = t >> 6, l = t & 63;
  int l31 = l & 31, h5 = l >> 5;
  int swV = (l31 & 7) << 4;
  int pl = (l31 & 0x13) | ((l31 & 4) << 1) | ((l31 & 8) >> 1);  // swap bits 2,3
  int swK = (pl & 7) << 4;
  int bn = blockIdx.x, qb = blockIdx.y;
  const char* qg = (const char*)(q_sd + (size_t)bn * 65536);   // [s][d]
  const char* kg = (const char*)(k_sd + (size_t)bn * 65536);   // [s][d]
  const char* vg = (const char*)(v_ds + (size_t)bn * 65536);   // [d][s]

  int q = qb * 256 + w * 32 + l31;
  short8 bq[4];
#pragma unroll
  for (int j = 0; j < 4; ++j)
    bq[j] = *(const short8*)(qg + (size_t)q * 128 + j * 32 + h5 * 16);

  f32x16 o_acc[2];
#pragma unroll
  for (int r = 0; r < 16; ++r) { o_acc[0][r] = 0.f; o_acc[1][r] = 0.f; }
  float l_run = 0.f;
  f32x16 zf;                       // persistent zero seed for QK^T chains
#pragma unroll
  for (int r = 0; r < 16; ++r) zf[r] = 0.f;

  int rowS = t >> 3;
  int offS = (t & 7) * 16;
  int swrS = (rowS & 7) << 4;
  {
    uint4 a = *(const uint4*)(kg + (size_t)t * 16);
    uint4 b2 = *(const uint4*)(vg + (size_t)rowS * 2048 + offS);
    *(uint4*)(K_lds[0] + ((t * 16) ^ swrS)) = a;
    *(uint4*)(V_lds[0] + ((t * 16) ^ swrS)) = b2;
  }
  __syncthreads();

  for (int kb = 0; kb < 16; ++kb) {
    int buf = kb & 1;
    uint4 pk, pv;
    if (kb < 15) {
      pk = *(const uint4*)(kg + (size_t)(kb + 1) * 8192 + (size_t)t * 16);
      pv = *(const uint4*)(vg + (size_t)rowS * 2048 + (size_t)(kb + 1) * 128 + offS);
    }
    short8 a_k[2][4];
#pragma unroll
    for (int kt = 0; kt < 2; ++kt)
#pragma unroll
      for (int j = 0; j < 4; ++j)
        a_k[kt][j] = *(const short8*)(K_lds[buf] +
            (((kt * 32 + pl) * 128 + j * 32 + h5 * 16) ^ swK));
    f32x16 s0, s1;
    __builtin_amdgcn_s_setprio(1);
    s0 = __builtin_amdgcn_mfma_f32_32x32x16_bf16(a_k[0][0], bq[0], zf, 0, 0, 0);
    s1 = __builtin_amdgcn_mfma_f32_32x32x16_bf16(a_k[1][0], bq[0], zf, 0, 0, 0);
#pragma unroll
    for (int j = 1; j < 4; ++j) {
      s0 = __builtin_amdgcn_mfma_f32_32x32x16_bf16(a_k[0][j], bq[j], s0, 0, 0, 0);
      s1 = __builtin_amdgcn_mfma_f32_32x32x16_bf16(a_k[1][j], bq[j], s1, 0, 0, 0);
    }
    __builtin_amdgcn_s_setprio(0);
    unsigned W0[8], W1[8];
    float ts = 0.f;
#pragma unroll
    for (int m = 0; m < 8; ++m) {
      float p0 = fexp2(s0[2 * m]), p1 = fexp2(s0[2 * m + 1]);
      float p2 = fexp2(s1[2 * m]), p3 = fexp2(s1[2 * m + 1]);
      ts += (p0 + p1) + (p2 + p3);
      W0[m] = cvt_pk(p0, p1);
      W1[m] = cvt_pk(p2, p3);
    }
    l_run += ts;
    short8 pb[4];
#pragma unroll
    for (int j = 0; j < 4; ++j) {
      uint4_t pw;
      if (j == 0)      pw = (uint4_t){W0[0], W0[1], W0[2], W0[3]};
      else if (j == 1) pw = (uint4_t){W0[4], W0[5], W0[6], W0[7]};
      else if (j == 2) pw = (uint4_t){W1[0], W1[1], W1[2], W1[3]};
      else             pw = (uint4_t){W1[4], W1[5], W1[6], W1[7]};
      pb[j] = __builtin_bit_cast(short8, pw);
    }
    short8 a_v[2][4];
#pragma unroll
    for (int dt = 0; dt < 2; ++dt)
#pragma unroll
      for (int j = 0; j < 4; ++j)
        a_v[dt][j] = *(const short8*)(V_lds[buf] +
            (((dt * 32 + l31) * 128 + j * 32 + h5 * 16) ^ swV));
    __builtin_amdgcn_s_setprio(1);
#pragma unroll
    for (int j = 0; j < 4; ++j) {
      o_acc[0] = __builtin_amdgcn_mfma_f32_32x32x16_bf16(a_v[0][j], pb[j], o_acc[0], 0, 0, 0);
      o_acc[1] = __builtin_amdgcn_mfma_f32_32x32x16_bf16(a_v[1][j], pb[j], o_acc[1], 0, 0, 0);
    }
    __builtin_amdgcn_s_setprio(0);
    if (kb < 15) {
      int nb = buf ^ 1;
      *(uint4*)(K_lds[nb] + ((t * 16) ^ swrS)) = pk;
      *(uint4*)(V_lds[nb] + ((t * 16) ^ swrS)) = pv;
    }
    __syncthreads();
  }
  int b_ = bn >> 3, n_ = bn & 7;
  float lsum = l_run + __shfl_xor(l_run, 32, 64);
  float invl = 1.0f / lsum;
  __hip_bfloat16* yrow = y_t + (size_t)b_ * 524288 + (size_t)q * 512 + n_ * 64 + h5 * 4;
#pragma unroll
  for (int dt = 0; dt < 2; ++dt) {
#pragma unroll
    for (int g4 = 0; g4 < 4; ++g4) {
      uint2 pr;
      pr.x = cvt_pk(o_acc[dt][4 * g4 + 0] * invl, o_acc[dt][4 * g4 + 1] * invl);
      pr.y = cvt_pk(o_acc[dt][4 * g4 + 2] * invl, o_acc[dt][4 * g4 + 3] * invl);
      *(uint2*)(yrow + dt * 32 + g4 * 8) = pr;
    }
  }
}

// ---------------------------------------------------------------------------
extern "C" void kernel_launch(void* const* d_in, const int* in_sizes, int n_in,
                              void* d_out, int out_size, void* d_ws, size_t ws_size,
                              hipStream_t stream) {
  const float* x      = (const float*)d_in[0];  // [16][512][1024]
  const float* w_attn = (const float*)d_in[1];  // [1536][512]
  const float* w_proj = (const float*)d_in[2];  // [512][512]
  float* out = (float*)d_out;

  // workspace (bf16 elements, ~69 MB total)
  __hip_bfloat16* wn_attn = (__hip_bfloat16*)d_ws;        // 786432
  __hip_bfloat16* wn_proj = wn_attn + 786432;             // 262144
  __hip_bfloat16* x_t     = wn_proj + 262144;             // 8388608
  __hip_bfloat16* y_t     = x_t;                          // alias (x_t dead after gemm_qkv)
  __hip_bfloat16* q_sd    = x_t + 8388608;                // 8388608
  __hip_bfloat16* k_sd    = q_sd + 8388608;               // 8388608
  __hip_bfloat16* v_ds    = k_sd + 8388608;               // 8388608

  prep_kernel<<<dim3(4096), dim3(256), 0, stream>>>(w_attn, w_proj, wn_attn, wn_proj, x, x_t);
  gemm_qkv<<<dim3(1536), dim3(256), 0, stream>>>(wn_attn, x_t, q_sd, k_sd, v_ds);
  attn_mfma<<<dim3(128, 4), dim3(512), 0, stream>>>(q_sd, k_sd, v_ds, y_t);
  gemm_proj<<<dim3(512), dim3(256), 0, stream>>>(wn_proj, y_t, out, x, 512);
}